// Round 7
// baseline (204.875 us; speedup 1.0000x reference)
//
#include <hip/hip_runtime.h>

#define TS 2048   // seq len
#define DM 1024   // d_model
#define KD 64     // k
#define NB 4      // batch

// ---------- workspace layout (float offsets) ----------
// WT_hi [192][1024] ushort : rows 0-63 Wq^T, 64-127 Wk^T, 128-191 Wv^T (bf16 hi)
// WT_lo [192][1024] ushort : bf16 residual (lo)
// bcomb [192] f32          : bq | bk | bv
// Qg    [8192][64] f32     : Q-only (for k_interout)
// P     [4][8192][192] f32 : split-K partials (k_qkv -> k_chunkred)
// Pf    [16][128][1024] f32: fold partials (k_prep -> k_fred), overlays P front
// O     [4][64][64][64] f32: per-chunk outer sums (k_chunkred -> k_interout)
// Yb    [8192][64] f32     : intra-chunk Y (k_chunkred -> k_interout)
// NOTE: O and Yb live AFTER P (no aliasing: k_chunkred reads P while writing
// O/Yb). Proven-safe pattern: kernel N writes, kernel N+1 consumes.
#define WTH_OFF 0
#define WTL_OFF 98304
#define BC_OFF  196608
#define QG_OFF  196864
#define P_OFF   1769728
#define PF_OFF  (P_OFF)
#define O_OFF   8061184
#define YB_OFF  9109760

typedef __attribute__((ext_vector_type(8))) short bf16x8;
typedef __attribute__((ext_vector_type(4))) float f32x4;

__device__ __forceinline__ ushort f2bf(float f) {
  unsigned u = __float_as_uint(f);
  unsigned r = u + 0x7FFFu + ((u >> 16) & 1u);
  return (ushort)(r >> 16);
}
__device__ __forceinline__ float bf2f(ushort h) {
  return __uint_as_float(((unsigned)h) << 16);
}

// ---------------- A1: split-K MFMA fold partials ----------------
__global__ __launch_bounds__(256) void k_prep(
    const float* __restrict__ W_pre, const float* __restrict__ Qf,
    const float* __restrict__ Kf, float* __restrict__ Pf) {
  const int d0 = blockIdx.x * 64;
  const int f = blockIdx.y;
  const int ks = blockIdx.z;
  const float* __restrict__ F = f ? Kf : Qf;
  const int tid = threadIdx.x;
  const int wave = tid >> 6, lane = tid & 63;
  const int quad = lane >> 4, l15 = lane & 15;
  __shared__ ushort As[64 * 72];
  __shared__ ushort Bs[64 * 72];
  f32x4 acc[4];
#pragma unroll
  for (int nt = 0; nt < 4; ++nt) acc[nt] = (f32x4){0.f, 0.f, 0.f, 0.f};

  const int ra = tid >> 3;
  const int c4 = (tid & 7) * 4;
  float4 aw[2];
  float bw[8];
  int t0 = ks * 128;
#pragma unroll
  for (int i = 0; i < 2; ++i)
    aw[i] = *(const float4*)&W_pre[(size_t)(d0 + i * 32 + ra) * TS + t0 + c4];
#pragma unroll
  for (int h = 0; h < 2; ++h)
#pragma unroll
    for (int u = 0; u < 4; ++u)
      bw[h * 4 + u] = F[(size_t)(t0 + (wave + 4 * h) * 4 + u) * KD + lane];

  for (int step = 0; step < 4; ++step) {
    __syncthreads();
#pragma unroll
    for (int i = 0; i < 2; ++i) {
      const int r = i * 32 + ra;
      const float4 v = aw[i];
      const ushort h0 = f2bf(v.x), h1 = f2bf(v.y), h2 = f2bf(v.z), h3 = f2bf(v.w);
      *(ushort4*)&As[r * 72 + c4] = make_ushort4(h0, h1, h2, h3);
      *(ushort4*)&As[r * 72 + 32 + c4] = make_ushort4(
          f2bf(v.x - bf2f(h0)), f2bf(v.y - bf2f(h1)),
          f2bf(v.z - bf2f(h2)), f2bf(v.w - bf2f(h3)));
    }
#pragma unroll
    for (int h = 0; h < 2; ++h) {
      const int gg = wave + 4 * h;
      ushort hh[4], ll[4];
#pragma unroll
      for (int u = 0; u < 4; ++u) {
        hh[u] = f2bf(bw[h * 4 + u]);
        ll[u] = f2bf(bw[h * 4 + u] - bf2f(hh[u]));
      }
      *(ushort4*)&Bs[lane * 72 + gg * 4] = make_ushort4(hh[0], hh[1], hh[2], hh[3]);
      *(ushort4*)&Bs[lane * 72 + 32 + gg * 4] = make_ushort4(ll[0], ll[1], ll[2], ll[3]);
    }
    __syncthreads();
    if (step < 3) {
      const int t1 = t0 + 32;
#pragma unroll
      for (int i = 0; i < 2; ++i)
        aw[i] = *(const float4*)&W_pre[(size_t)(d0 + i * 32 + ra) * TS + t1 + c4];
#pragma unroll
      for (int h = 0; h < 2; ++h)
#pragma unroll
        for (int u = 0; u < 4; ++u)
          bw[h * 4 + u] = F[(size_t)(t1 + (wave + 4 * h) * 4 + u) * KD + lane];
    }
    const ushort* ap = &As[(wave * 16 + l15) * 72 + quad * 8];
    const bf16x8 a_h = *(const bf16x8*)ap;
    const bf16x8 a_l = *(const bf16x8*)(ap + 32);
#pragma unroll
    for (int nt = 0; nt < 4; ++nt) {
      const ushort* bp = &Bs[(nt * 16 + l15) * 72 + quad * 8];
      const bf16x8 b_h = *(const bf16x8*)bp;
      const bf16x8 b_l = *(const bf16x8*)(bp + 32);
      acc[nt] = __builtin_amdgcn_mfma_f32_16x16x32_bf16(a_h, b_h, acc[nt], 0, 0, 0);
      acc[nt] = __builtin_amdgcn_mfma_f32_16x16x32_bf16(a_h, b_l, acc[nt], 0, 0, 0);
      acc[nt] = __builtin_amdgcn_mfma_f32_16x16x32_bf16(a_l, b_h, acc[nt], 0, 0, 0);
    }
    t0 += 32;
  }
#pragma unroll
  for (int nt = 0; nt < 4; ++nt) {
    const int n = f * 64 + nt * 16 + l15;
#pragma unroll
    for (int r = 0; r < 4; ++r) {
      const int d = d0 + wave * 16 + quad * 4 + r;
      Pf[((size_t)ks * 128 + n) * DM + d] = acc[nt][r];
    }
  }
}

// ---------------- A2: reduce fold partials -> WT hi/lo; Wv transpose; bias ----------------
__global__ __launch_bounds__(256) void k_fred(
    const float* __restrict__ Pf, const float* __restrict__ Wv,
    const float* __restrict__ b_pre, const float* __restrict__ Qf,
    const float* __restrict__ Kf, const float* __restrict__ bv,
    ushort* __restrict__ WT_hi, ushort* __restrict__ WT_lo,
    float* __restrict__ bcomb) {
  const int bx = blockIdx.x;
  const int tid = threadIdx.x;
  if (bx < 32) {
    const int n0 = bx * 4;
    const int d4 = tid * 4;
#pragma unroll
    for (int j = 0; j < 4; ++j) {
      const int n = n0 + j;
      float4 s = {0.f, 0.f, 0.f, 0.f};
#pragma unroll
      for (int ks = 0; ks < 16; ++ks) {
        const float4 v = *(const float4*)&Pf[((size_t)ks * 128 + n) * DM + d4];
        s.x += v.x; s.y += v.y; s.z += v.z; s.w += v.w;
      }
      const ushort h0 = f2bf(s.x), h1 = f2bf(s.y), h2 = f2bf(s.z), h3 = f2bf(s.w);
      *(ushort4*)&WT_hi[(size_t)n * DM + d4] = make_ushort4(h0, h1, h2, h3);
      *(ushort4*)&WT_lo[(size_t)n * DM + d4] = make_ushort4(
          f2bf(s.x - bf2f(h0)), f2bf(s.y - bf2f(h1)),
          f2bf(s.z - bf2f(h2)), f2bf(s.w - bf2f(h3)));
    }
    const float* __restrict__ F = (n0 < 64) ? Qf : Kf;
    const int c0 = n0 & 63;
    __shared__ float bred[4][256];
    float p[4] = {0.f, 0.f, 0.f, 0.f};
#pragma unroll
    for (int u = 0; u < 8; ++u) {
      const int t = tid * 8 + u;
      const float bp = b_pre[t];
#pragma unroll
      for (int j = 0; j < 4; ++j) p[j] += bp * F[(size_t)t * KD + c0 + j];
    }
#pragma unroll
    for (int j = 0; j < 4; ++j) bred[j][tid] = p[j];
    __syncthreads();
    for (int s = 128; s > 0; s >>= 1) {
      if (tid < s) {
#pragma unroll
        for (int j = 0; j < 4; ++j) bred[j][tid] += bred[j][tid + s];
      }
      __syncthreads();
    }
    if (tid < 4) bcomb[n0 + tid] = bred[tid][0];
  } else {
    const int n0 = 128 + (bx - 32) * 4;
    const int d4 = tid * 4;
#pragma unroll
    for (int j = 0; j < 4; ++j) {
      const int c = n0 - 128 + j;
      float v[4];
#pragma unroll
      for (int i = 0; i < 4; ++i) v[i] = Wv[(size_t)(d4 + i) * KD + c];
      const ushort h0 = f2bf(v[0]), h1 = f2bf(v[1]), h2 = f2bf(v[2]), h3 = f2bf(v[3]);
      *(ushort4*)&WT_hi[(size_t)(n0 + j) * DM + d4] = make_ushort4(h0, h1, h2, h3);
      *(ushort4*)&WT_lo[(size_t)(n0 + j) * DM + d4] = make_ushort4(
          f2bf(v[0] - bf2f(h0)), f2bf(v[1] - bf2f(h1)),
          f2bf(v[2] - bf2f(h2)), f2bf(v[3] - bf2f(h3)));
    }
    if (tid < 4) bcomb[n0 + tid] = bv[n0 - 128 + tid];
  }
}

// ---------------- B: split-K MFMA bf16x3 GEMM  P[ks] = x[:, ks*256:+256] @ W ----------------
__global__ __launch_bounds__(256) void k_qkv(
    const float* __restrict__ x, const ushort* __restrict__ WT_hi,
    const ushort* __restrict__ WT_lo, float* __restrict__ P) {
  const int row0 = blockIdx.x * 64;
  const int ks = blockIdx.y;
  const int tid = threadIdx.x;
  const int wave = tid >> 6, lane = tid & 63;
  const int quad = lane >> 4, l15 = lane & 15;
  const int n0 = wave * 48;
  __shared__ ushort As[64 * 72];
  __shared__ ushort Bs[192 * 72];
  f32x4 acc[4][3];
#pragma unroll
  for (int mt = 0; mt < 4; ++mt)
#pragma unroll
    for (int nt = 0; nt < 3; ++nt) acc[mt][nt] = (f32x4){0.f, 0.f, 0.f, 0.f};

  for (int step = 0; step < 8; ++step) {
    const int kk = ks * 256 + step * 32;
    __syncthreads();
#pragma unroll
    for (int i = 0; i < 2; ++i) {
      const int idx = i * 256 + tid;
      const int r = idx >> 3, c4 = (idx & 7) * 4;
      const float4 v = *(const float4*)&x[(size_t)(row0 + r) * DM + kk + c4];
      const ushort h0 = f2bf(v.x), h1 = f2bf(v.y), h2 = f2bf(v.z), h3 = f2bf(v.w);
      *(ushort4*)&As[r * 72 + c4] = make_ushort4(h0, h1, h2, h3);
      *(ushort4*)&As[r * 72 + 32 + c4] = make_ushort4(
          f2bf(v.x - bf2f(h0)), f2bf(v.y - bf2f(h1)),
          f2bf(v.z - bf2f(h2)), f2bf(v.w - bf2f(h3)));
    }
#pragma unroll
    for (int i = 0; i < 6; ++i) {
      const int idx = i * 256 + tid;
      const int half = idx >= 768;
      const int j = half ? idx - 768 : idx;
      const int n = j >> 2, ch = j & 3;
      const ushort* src = (half ? WT_lo : WT_hi) + (size_t)n * DM + kk + ch * 8;
      *(float4*)&Bs[n * 72 + half * 32 + ch * 8] = *(const float4*)src;
    }
    __syncthreads();
    bf16x8 a_h[4], a_l[4], b_h[3], b_l[3];
#pragma unroll
    for (int mt = 0; mt < 4; ++mt) {
      const ushort* p = &As[(mt * 16 + l15) * 72 + quad * 8];
      a_h[mt] = *(const bf16x8*)p;
      a_l[mt] = *(const bf16x8*)(p + 32);
    }
#pragma unroll
    for (int nt = 0; nt < 3; ++nt) {
      const ushort* p = &Bs[(n0 + nt * 16 + l15) * 72 + quad * 8];
      b_h[nt] = *(const bf16x8*)p;
      b_l[nt] = *(const bf16x8*)(p + 32);
    }
#pragma unroll
    for (int mt = 0; mt < 4; ++mt)
#pragma unroll
      for (int nt = 0; nt < 3; ++nt) {
        acc[mt][nt] = __builtin_amdgcn_mfma_f32_16x16x32_bf16(a_h[mt], b_h[nt], acc[mt][nt], 0, 0, 0);
        acc[mt][nt] = __builtin_amdgcn_mfma_f32_16x16x32_bf16(a_h[mt], b_l[nt], acc[mt][nt], 0, 0, 0);
        acc[mt][nt] = __builtin_amdgcn_mfma_f32_16x16x32_bf16(a_l[mt], b_h[nt], acc[mt][nt], 0, 0, 0);
      }
  }
  float* Pp = P + (size_t)ks * TS * NB * 192;
#pragma unroll
  for (int mt = 0; mt < 4; ++mt) {
    const int rbase = row0 + mt * 16 + quad * 4;
#pragma unroll
    for (int nt = 0; nt < 3; ++nt) {
      const int col = n0 + nt * 16 + l15;
#pragma unroll
      for (int r = 0; r < 4; ++r)
        Pp[(size_t)(rbase + r) * 192 + col] = acc[mt][nt][r];
    }
  }
}

// ---------------- C1: fused split-K reduce + per-chunk intra + outer sums ----------------
// grid (64, 4), 256 threads. Reads P (4 slices) + bcomb; writes Qg, Yb, O.
__global__ __launch_bounds__(256) void k_chunkred(
    const float* __restrict__ P, const float* __restrict__ bcomb,
    const float* __restrict__ decay, float* __restrict__ Qg,
    float* __restrict__ Yb, float* __restrict__ O) {
  const int c = blockIdx.x;
  const int b = blockIdx.y;
  const int s0 = c * 32;
  const int tid = threadIdx.x;
  __shared__ float Qs[32][68], Ks[32][68], Vs[32][68];
  __shared__ float Ss[32][36];
  __shared__ float dec[32];
  const size_t NTOT = (size_t)TS * NB * 192;

  for (int idx = tid; idx < 32 * 48; idx += 256) {
    const int r = idx / 48, cq = (idx % 48) * 4;
    const size_t g = (size_t)(b * TS + s0 + r) * 192 + cq;
    float4 a = *(const float4*)&P[g];
    const float4 b2 = *(const float4*)&P[NTOT + g];
    const float4 c2 = *(const float4*)&P[2 * NTOT + g];
    const float4 d2 = *(const float4*)&P[3 * NTOT + g];
    const float4 bi = *(const float4*)&bcomb[cq];
    a.x += b2.x + c2.x + d2.x + bi.x;
    a.y += b2.y + c2.y + d2.y + bi.y;
    a.z += b2.z + c2.z + d2.z + bi.z;
    a.w += b2.w + c2.w + d2.w + bi.w;
    if (cq < 64) {
      *(float4*)&Qs[r][cq] = a;
      *(float4*)&Qg[(size_t)(b * TS + s0 + r) * KD + cq] = a;
    } else if (cq < 128) {
      *(float4*)&Ks[r][cq - 64] = a;
    } else {
      *(float4*)&Vs[r][cq - 128] = a;
    }
  }
  if (tid < 32) dec[tid] = decay[s0 + tid];
  __syncthreads();

  {
    const int sc = (tid & 15) * 2;
    const int tr = (tid >> 4) * 2;
    float a00 = 0.f, a01 = 0.f, a10 = 0.f, a11 = 0.f;
#pragma unroll
    for (int k = 0; k < 64; k += 4) {
      const float4 q0 = *(const float4*)&Qs[tr][k];
      const float4 q1 = *(const float4*)&Qs[tr + 1][k];
      const float4 v0 = *(const float4*)&Vs[sc][k];
      const float4 v1 = *(const float4*)&Vs[sc + 1][k];
      a00 += q0.x * v0.x + q0.y * v0.y + q0.z * v0.z + q0.w * v0.w;
      a01 += q0.x * v1.x + q0.y * v1.y + q0.z * v1.z + q0.w * v1.w;
      a10 += q1.x * v0.x + q1.y * v0.y + q1.z * v0.z + q1.w * v0.w;
      a11 += q1.x * v1.x + q1.y * v1.y + q1.z * v1.z + q1.w * v1.w;
    }
    const float d0 = dec[sc], d1 = dec[sc + 1];
    Ss[tr][sc]         = (sc     <= tr)     ? a00 * d0 : 0.f;
    Ss[tr][sc + 1]     = (sc + 1 <= tr)     ? a01 * d1 : 0.f;
    Ss[tr + 1][sc]     = (sc     <= tr + 1) ? a10 * d0 : 0.f;
    Ss[tr + 1][sc + 1] = (sc + 1 <= tr + 1) ? a11 * d1 : 0.f;
  }

  float o[4][4];
#pragma unroll
  for (int i = 0; i < 4; ++i)
#pragma unroll
    for (int j = 0; j < 4; ++j) o[i][j] = 0.f;
  {
    const int kx = (tid & 15) * 4;
    const int nx = (tid >> 4) * 4;
#pragma unroll
    for (int s = 0; s < 32; ++s) {
      const float ds = dec[s];
      float4 v4 = *(const float4*)&Vs[s][kx];
      const float4 k4 = *(const float4*)&Ks[s][nx];
      v4.x *= ds; v4.y *= ds; v4.z *= ds; v4.w *= ds;
      o[0][0] += v4.x * k4.x; o[0][1] += v4.x * k4.y; o[0][2] += v4.x * k4.z; o[0][3] += v4.x * k4.w;
      o[1][0] += v4.y * k4.x; o[1][1] += v4.y * k4.y; o[1][2] += v4.y * k4.z; o[1][3] += v4.y * k4.w;
      o[2][0] += v4.z * k4.x; o[2][1] += v4.z * k4.y; o[2][2] += v4.z * k4.z; o[2][3] += v4.z * k4.w;
      o[3][0] += v4.w * k4.x; o[3][1] += v4.w * k4.y; o[3][2] += v4.w * k4.z; o[3][3] += v4.w * k4.w;
    }
  }
  __syncthreads();

  {
    const int nx = (tid & 15) * 4;
    const int tr = (tid >> 4) * 2;
    float y0[4] = {0.f, 0.f, 0.f, 0.f};
    float y1[4] = {0.f, 0.f, 0.f, 0.f};
#pragma unroll
    for (int s = 0; s < 32; s += 4) {
      const float4 sa = *(const float4*)&Ss[tr][s];
      const float4 sb = *(const float4*)&Ss[tr + 1][s];
#pragma unroll
      for (int u = 0; u < 4; ++u) {
        const float4 k4 = *(const float4*)&Ks[s + u][nx];
        const float su0 = (u == 0) ? sa.x : (u == 1) ? sa.y : (u == 2) ? sa.z : sa.w;
        const float su1 = (u == 0) ? sb.x : (u == 1) ? sb.y : (u == 2) ? sb.z : sb.w;
        y0[0] += su0 * k4.x; y0[1] += su0 * k4.y; y0[2] += su0 * k4.z; y0[3] += su0 * k4.w;
        y1[0] += su1 * k4.x; y1[1] += su1 * k4.y; y1[2] += su1 * k4.z; y1[3] += su1 * k4.w;
      }
    }
    float4 w0, w1;
    w0.x = y0[0]; w0.y = y0[1]; w0.z = y0[2]; w0.w = y0[3];
    w1.x = y1[0]; w1.y = y1[1]; w1.z = y1[2]; w1.w = y1[3];
    *(float4*)&Yb[(size_t)(b * TS + s0 + tr) * KD + nx] = w0;
    *(float4*)&Yb[(size_t)(b * TS + s0 + tr + 1) * KD + nx] = w1;
  }

  {
    const int kx = (tid & 15) * 4;
    const int nx = (tid >> 4) * 4;
    const size_t base = ((size_t)(b * 64 + c) * 64) * 64;
#pragma unroll
    for (int i = 0; i < 4; ++i) {
      float4 w;
      w.x = o[i][0]; w.y = o[i][1]; w.z = o[i][2]; w.w = o[i][3];
      *(float4*)&O[base + (size_t)(kx + i) * 64 + nx] = w;
    }
  }
}

// ---------------- C2: fused chunk-prefix + inter-chunk attention + output GEMM ----------------
// grid (64, 4), 256 threads. Block c: State = sum_{c'<c} O[c'] (registers),
// y = Yb + Q@State, out = y @ W_o + b_o.
__global__ __launch_bounds__(256) void k_interout(
    const float* __restrict__ O, const float* __restrict__ Qg,
    const float* __restrict__ Yb, const float* __restrict__ Wo,
    const float* __restrict__ bo, float* __restrict__ out) {
  const int c = blockIdx.x;
  const int b = blockIdx.y;
  const int t0 = c * 32;
  const int tid = threadIdx.x;
  __shared__ float Sts[64][68];
  __shared__ float Qs[32][68];
  __shared__ float Yrow[32][68];

  // exclusive prefix of O over chunks, in registers (thread owns 16 floats)
  float4 st[4];
#pragma unroll
  for (int g = 0; g < 4; ++g) st[g] = (float4){0.f, 0.f, 0.f, 0.f};
  const size_t ob = (size_t)b * 64 * 4096;
  for (int cp = 0; cp < c; ++cp) {
#pragma unroll
    for (int g = 0; g < 4; ++g) {
      const float4 v = *(const float4*)&O[ob + (size_t)cp * 4096 + g * 1024 + tid * 4];
      st[g].x += v.x; st[g].y += v.y; st[g].z += v.z; st[g].w += v.w;
    }
  }
#pragma unroll
  for (int g = 0; g < 4; ++g)
    *(float4*)&Sts[g * 16 + (tid >> 4)][(tid & 15) * 4] = st[g];

#pragma unroll
  for (int i = 0; i < 2; ++i) {
    const int idx = i * 256 + tid;
    const int r = idx >> 4, q = (idx & 15) * 4;
    *(float4*)&Qs[r][q] = *(const float4*)&Qg[(size_t)(b * TS + t0 + r) * KD + q];
    *(float4*)&Yrow[r][q] = *(const float4*)&Yb[(size_t)(b * TS + t0 + r) * KD + q];
  }
  __syncthreads();

  {
    const int nx = (tid & 15) * 4;
    const int tr = (tid >> 4) * 2;
    float y0[4] = {0.f, 0.f, 0.f, 0.f};
    float y1[4] = {0.f, 0.f, 0.f, 0.f};
#pragma unroll
    for (int k = 0; k < 64; k += 4) {
      const float4 q0 = *(const float4*)&Qs[tr][k];
      const float4 q1 = *(const float4*)&Qs[tr + 1][k];
#pragma unroll
      for (int u = 0; u < 4; ++u) {
        const float4 s4 = *(const float4*)&Sts[k + u][nx];
        const float a0 = (u == 0) ? q0.x : (u == 1) ? q0.y : (u == 2) ? q0.z : q0.w;
        const float a1 = (u == 0) ? q1.x : (u == 1) ? q1.y : (u == 2) ? q1.z : q1.w;
        y0[0] += a0 * s4.x; y0[1] += a0 * s4.y; y0[2] += a0 * s4.z; y0[3] += a0 * s4.w;
        y1[0] += a1 * s4.x; y1[1] += a1 * s4.y; y1[2] += a1 * s4.z; y1[3] += a1 * s4.w;
      }
    }
    float4 p0 = *(const float4*)&Yrow[tr][nx];
    float4 p1 = *(const float4*)&Yrow[tr + 1][nx];
    p0.x += y0[0]; p0.y += y0[1]; p0.z += y0[2]; p0.w += y0[3];
    p1.x += y1[0]; p1.y += y1[1]; p1.z += y1[2]; p1.w += y1[3];
    *(float4*)&Yrow[tr][nx] = p0;
    *(float4*)&Yrow[tr + 1][nx] = p1;
  }
  __syncthreads();

  const int d0 = tid * 4;
  const float4 b4 = *(const float4*)&bo[d0];
#pragma unroll
  for (int pass = 0; pass < 2; ++pass) {
    float acc[16][4];
#pragma unroll
    for (int r = 0; r < 16; ++r)
#pragma unroll
      for (int j = 0; j < 4; ++j) acc[r][j] = 0.f;
    for (int k = 0; k < 64; k += 4) {
      const float4 w0 = *(const float4*)&Wo[(size_t)(k + 0) * DM + d0];
      const float4 w1 = *(const float4*)&Wo[(size_t)(k + 1) * DM + d0];
      const float4 w2 = *(const float4*)&Wo[(size_t)(k + 2) * DM + d0];
      const float4 w3 = *(const float4*)&Wo[(size_t)(k + 3) * DM + d0];
#pragma unroll
      for (int r = 0; r < 16; ++r) {
        const float4 ys = *(const float4*)&Yrow[pass * 16 + r][k];
        acc[r][0] += ys.x * w0.x + ys.y * w1.x + ys.z * w2.x + ys.w * w3.x;
        acc[r][1] += ys.x * w0.y + ys.y * w1.y + ys.z * w2.y + ys.w * w3.y;
        acc[r][2] += ys.x * w0.z + ys.y * w1.z + ys.z * w2.z + ys.w * w3.z;
        acc[r][3] += ys.x * w0.w + ys.y * w1.w + ys.z * w2.w + ys.w * w3.w;
      }
    }
#pragma unroll
    for (int r = 0; r < 16; ++r) {
      float4 w;
      w.x = acc[r][0] + b4.x;
      w.y = acc[r][1] + b4.y;
      w.z = acc[r][2] + b4.z;
      w.w = acc[r][3] + b4.w;
      *(float4*)&out[(size_t)(b * TS + t0 + pass * 16 + r) * DM + d0] = w;
    }
  }
}

extern "C" void kernel_launch(void* const* d_in, const int* in_sizes, int n_in,
                              void* d_out, int out_size, void* d_ws, size_t ws_size,
                              hipStream_t stream) {
  const float* x     = (const float*)d_in[0];
  const float* W_pre = (const float*)d_in[1];
  const float* b_pre = (const float*)d_in[2];
  const float* Qf    = (const float*)d_in[3];
  const float* Kf    = (const float*)d_in[4];
  const float* W_v   = (const float*)d_in[5];
  const float* b_v   = (const float*)d_in[6];
  const float* W_o   = (const float*)d_in[7];
  const float* b_o   = (const float*)d_in[8];
  const float* decay = (const float*)d_in[9];
  float* out = (float*)d_out;
  float* ws = (float*)d_ws;

  ushort* WT_hi = (ushort*)(ws + WTH_OFF);
  ushort* WT_lo = (ushort*)(ws + WTL_OFF);
  float* bcomb = ws + BC_OFF;
  float* Qg    = ws + QG_OFF;
  float* P     = ws + P_OFF;
  float* Pf    = ws + PF_OFF;
  float* O     = ws + O_OFF;
  float* Yb    = ws + YB_OFF;

  k_prep<<<dim3(16, 2, 16), 256, 0, stream>>>(W_pre, Qf, Kf, Pf);
  k_fred<<<dim3(48), 256, 0, stream>>>(Pf, W_v, b_pre, Qf, Kf, b_v,
                                       WT_hi, WT_lo, bcomb);
  k_qkv<<<dim3(NB * TS / 64, 4), 256, 0, stream>>>(x, WT_hi, WT_lo, P);
  k_chunkred<<<dim3(TS / 32, NB), 256, 0, stream>>>(P, bcomb, decay, Qg, Yb, O);
  k_interout<<<dim3(TS / 32, NB), 256, 0, stream>>>(O, Qg, Yb, W_o, b_o, out);
}

// Round 8
// 196.301 us; speedup vs baseline: 1.0437x; 1.0437x over previous
//
#include <hip/hip_runtime.h>

#define TS 2048   // seq len
#define DM 1024   // d_model
#define KD 64     // k
#define NB 4      // batch

// ---------- workspace layout (float offsets) ----------
// WT_hi [192][1024] ushort : rows 0-63 Wq^T, 64-127 Wk^T, 128-191 Wv^T (bf16 hi)
// WT_lo [192][1024] ushort : bf16 residual (lo)
// bcomb [192] f32          : bq | bk | bv
// Qg    [8192][64] f32     : Q-only (k_chunkred -> k_interout)
// P     [4][8192][192] f32 : split-K partials (k_qkv -> k_chunkred)
// Pf    [16][128][1024] f32: fold partials (k_prep -> k_fred), overlays P front
// St    [4][64][64][64] f32: exclusive chunk-prefix (k_scan -> k_interout),
//                            overlays dead P region (P consumed by k_chunkred)
// O     [4][64][64][64] f32: per-chunk outer sums (k_chunkred -> k_scan/k_interout)
// Yb    [8192][64] f32     : intra-chunk Y (k_chunkred -> k_interout)
#define WTH_OFF 0
#define WTL_OFF 98304
#define BC_OFF  196608
#define QG_OFF  196864
#define P_OFF   1769728
#define PF_OFF  (P_OFF)
#define ST_OFF  (P_OFF)
#define O_OFF   8061184
#define YB_OFF  9109760

typedef __attribute__((ext_vector_type(8))) short bf16x8;
typedef __attribute__((ext_vector_type(4))) float f32x4;

__device__ __forceinline__ ushort f2bf(float f) {
  unsigned u = __float_as_uint(f);
  unsigned r = u + 0x7FFFu + ((u >> 16) & 1u);
  return (ushort)(r >> 16);
}
__device__ __forceinline__ float bf2f(ushort h) {
  return __uint_as_float(((unsigned)h) << 16);
}

// ---------------- A1: split-K MFMA fold partials ----------------
__global__ __launch_bounds__(256) void k_prep(
    const float* __restrict__ W_pre, const float* __restrict__ Qf,
    const float* __restrict__ Kf, float* __restrict__ Pf) {
  const int d0 = blockIdx.x * 64;
  const int f = blockIdx.y;
  const int ks = blockIdx.z;
  const float* __restrict__ F = f ? Kf : Qf;
  const int tid = threadIdx.x;
  const int wave = tid >> 6, lane = tid & 63;
  const int quad = lane >> 4, l15 = lane & 15;
  __shared__ ushort As[64 * 72];
  __shared__ ushort Bs[64 * 72];
  f32x4 acc[4];
#pragma unroll
  for (int nt = 0; nt < 4; ++nt) acc[nt] = (f32x4){0.f, 0.f, 0.f, 0.f};

  const int ra = tid >> 3;
  const int c4 = (tid & 7) * 4;
  float4 aw[2];
  float bw[8];
  int t0 = ks * 128;
#pragma unroll
  for (int i = 0; i < 2; ++i)
    aw[i] = *(const float4*)&W_pre[(size_t)(d0 + i * 32 + ra) * TS + t0 + c4];
#pragma unroll
  for (int h = 0; h < 2; ++h)
#pragma unroll
    for (int u = 0; u < 4; ++u)
      bw[h * 4 + u] = F[(size_t)(t0 + (wave + 4 * h) * 4 + u) * KD + lane];

  for (int step = 0; step < 4; ++step) {
    __syncthreads();
#pragma unroll
    for (int i = 0; i < 2; ++i) {
      const int r = i * 32 + ra;
      const float4 v = aw[i];
      const ushort h0 = f2bf(v.x), h1 = f2bf(v.y), h2 = f2bf(v.z), h3 = f2bf(v.w);
      *(ushort4*)&As[r * 72 + c4] = make_ushort4(h0, h1, h2, h3);
      *(ushort4*)&As[r * 72 + 32 + c4] = make_ushort4(
          f2bf(v.x - bf2f(h0)), f2bf(v.y - bf2f(h1)),
          f2bf(v.z - bf2f(h2)), f2bf(v.w - bf2f(h3)));
    }
#pragma unroll
    for (int h = 0; h < 2; ++h) {
      const int gg = wave + 4 * h;
      ushort hh[4], ll[4];
#pragma unroll
      for (int u = 0; u < 4; ++u) {
        hh[u] = f2bf(bw[h * 4 + u]);
        ll[u] = f2bf(bw[h * 4 + u] - bf2f(hh[u]));
      }
      *(ushort4*)&Bs[lane * 72 + gg * 4] = make_ushort4(hh[0], hh[1], hh[2], hh[3]);
      *(ushort4*)&Bs[lane * 72 + 32 + gg * 4] = make_ushort4(ll[0], ll[1], ll[2], ll[3]);
    }
    __syncthreads();
    if (step < 3) {
      const int t1 = t0 + 32;
#pragma unroll
      for (int i = 0; i < 2; ++i)
        aw[i] = *(const float4*)&W_pre[(size_t)(d0 + i * 32 + ra) * TS + t1 + c4];
#pragma unroll
      for (int h = 0; h < 2; ++h)
#pragma unroll
        for (int u = 0; u < 4; ++u)
          bw[h * 4 + u] = F[(size_t)(t1 + (wave + 4 * h) * 4 + u) * KD + lane];
    }
    const ushort* ap = &As[(wave * 16 + l15) * 72 + quad * 8];
    const bf16x8 a_h = *(const bf16x8*)ap;
    const bf16x8 a_l = *(const bf16x8*)(ap + 32);
#pragma unroll
    for (int nt = 0; nt < 4; ++nt) {
      const ushort* bp = &Bs[(nt * 16 + l15) * 72 + quad * 8];
      const bf16x8 b_h = *(const bf16x8*)bp;
      const bf16x8 b_l = *(const bf16x8*)(bp + 32);
      acc[nt] = __builtin_amdgcn_mfma_f32_16x16x32_bf16(a_h, b_h, acc[nt], 0, 0, 0);
      acc[nt] = __builtin_amdgcn_mfma_f32_16x16x32_bf16(a_h, b_l, acc[nt], 0, 0, 0);
      acc[nt] = __builtin_amdgcn_mfma_f32_16x16x32_bf16(a_l, b_h, acc[nt], 0, 0, 0);
    }
    t0 += 32;
  }
#pragma unroll
  for (int nt = 0; nt < 4; ++nt) {
    const int n = f * 64 + nt * 16 + l15;
#pragma unroll
    for (int r = 0; r < 4; ++r) {
      const int d = d0 + wave * 16 + quad * 4 + r;
      Pf[((size_t)ks * 128 + n) * DM + d] = acc[nt][r];
    }
  }
}

// ---------------- A2: reduce fold partials -> WT hi/lo; Wv transpose; bias ----------------
__global__ __launch_bounds__(256) void k_fred(
    const float* __restrict__ Pf, const float* __restrict__ Wv,
    const float* __restrict__ b_pre, const float* __restrict__ Qf,
    const float* __restrict__ Kf, const float* __restrict__ bv,
    ushort* __restrict__ WT_hi, ushort* __restrict__ WT_lo,
    float* __restrict__ bcomb) {
  const int bx = blockIdx.x;
  const int tid = threadIdx.x;
  if (bx < 32) {
    const int n0 = bx * 4;
    const int d4 = tid * 4;
#pragma unroll
    for (int j = 0; j < 4; ++j) {
      const int n = n0 + j;
      float4 s = {0.f, 0.f, 0.f, 0.f};
#pragma unroll
      for (int ks = 0; ks < 16; ++ks) {
        const float4 v = *(const float4*)&Pf[((size_t)ks * 128 + n) * DM + d4];
        s.x += v.x; s.y += v.y; s.z += v.z; s.w += v.w;
      }
      const ushort h0 = f2bf(s.x), h1 = f2bf(s.y), h2 = f2bf(s.z), h3 = f2bf(s.w);
      *(ushort4*)&WT_hi[(size_t)n * DM + d4] = make_ushort4(h0, h1, h2, h3);
      *(ushort4*)&WT_lo[(size_t)n * DM + d4] = make_ushort4(
          f2bf(s.x - bf2f(h0)), f2bf(s.y - bf2f(h1)),
          f2bf(s.z - bf2f(h2)), f2bf(s.w - bf2f(h3)));
    }
    const float* __restrict__ F = (n0 < 64) ? Qf : Kf;
    const int c0 = n0 & 63;
    __shared__ float bred[4][256];
    float p[4] = {0.f, 0.f, 0.f, 0.f};
#pragma unroll
    for (int u = 0; u < 8; ++u) {
      const int t = tid * 8 + u;
      const float bp = b_pre[t];
#pragma unroll
      for (int j = 0; j < 4; ++j) p[j] += bp * F[(size_t)t * KD + c0 + j];
    }
#pragma unroll
    for (int j = 0; j < 4; ++j) bred[j][tid] = p[j];
    __syncthreads();
    for (int s = 128; s > 0; s >>= 1) {
      if (tid < s) {
#pragma unroll
        for (int j = 0; j < 4; ++j) bred[j][tid] += bred[j][tid + s];
      }
      __syncthreads();
    }
    if (tid < 4) bcomb[n0 + tid] = bred[tid][0];
  } else {
    const int n0 = 128 + (bx - 32) * 4;
    const int d4 = tid * 4;
#pragma unroll
    for (int j = 0; j < 4; ++j) {
      const int c = n0 - 128 + j;
      float v[4];
#pragma unroll
      for (int i = 0; i < 4; ++i) v[i] = Wv[(size_t)(d4 + i) * KD + c];
      const ushort h0 = f2bf(v[0]), h1 = f2bf(v[1]), h2 = f2bf(v[2]), h3 = f2bf(v[3]);
      *(ushort4*)&WT_hi[(size_t)(n0 + j) * DM + d4] = make_ushort4(h0, h1, h2, h3);
      *(ushort4*)&WT_lo[(size_t)(n0 + j) * DM + d4] = make_ushort4(
          f2bf(v[0] - bf2f(h0)), f2bf(v[1] - bf2f(h1)),
          f2bf(v[2] - bf2f(h2)), f2bf(v[3] - bf2f(h3)));
    }
    if (tid < 4) bcomb[n0 + tid] = bv[n0 - 128 + tid];
  }
}

// ---------------- B: split-K MFMA bf16x3 GEMM  P[ks] = x[:, ks*256:+256] @ W ----------------
__global__ __launch_bounds__(256) void k_qkv(
    const float* __restrict__ x, const ushort* __restrict__ WT_hi,
    const ushort* __restrict__ WT_lo, float* __restrict__ P) {
  const int row0 = blockIdx.x * 64;
  const int ks = blockIdx.y;
  const int tid = threadIdx.x;
  const int wave = tid >> 6, lane = tid & 63;
  const int quad = lane >> 4, l15 = lane & 15;
  const int n0 = wave * 48;
  __shared__ ushort As[64 * 72];
  __shared__ ushort Bs[192 * 72];
  f32x4 acc[4][3];
#pragma unroll
  for (int mt = 0; mt < 4; ++mt)
#pragma unroll
    for (int nt = 0; nt < 3; ++nt) acc[mt][nt] = (f32x4){0.f, 0.f, 0.f, 0.f};

  for (int step = 0; step < 8; ++step) {
    const int kk = ks * 256 + step * 32;
    __syncthreads();
#pragma unroll
    for (int i = 0; i < 2; ++i) {
      const int idx = i * 256 + tid;
      const int r = idx >> 3, c4 = (idx & 7) * 4;
      const float4 v = *(const float4*)&x[(size_t)(row0 + r) * DM + kk + c4];
      const ushort h0 = f2bf(v.x), h1 = f2bf(v.y), h2 = f2bf(v.z), h3 = f2bf(v.w);
      *(ushort4*)&As[r * 72 + c4] = make_ushort4(h0, h1, h2, h3);
      *(ushort4*)&As[r * 72 + 32 + c4] = make_ushort4(
          f2bf(v.x - bf2f(h0)), f2bf(v.y - bf2f(h1)),
          f2bf(v.z - bf2f(h2)), f2bf(v.w - bf2f(h3)));
    }
#pragma unroll
    for (int i = 0; i < 6; ++i) {
      const int idx = i * 256 + tid;
      const int half = idx >= 768;
      const int j = half ? idx - 768 : idx;
      const int n = j >> 2, ch = j & 3;
      const ushort* src = (half ? WT_lo : WT_hi) + (size_t)n * DM + kk + ch * 8;
      *(float4*)&Bs[n * 72 + half * 32 + ch * 8] = *(const float4*)src;
    }
    __syncthreads();
    bf16x8 a_h[4], a_l[4], b_h[3], b_l[3];
#pragma unroll
    for (int mt = 0; mt < 4; ++mt) {
      const ushort* p = &As[(mt * 16 + l15) * 72 + quad * 8];
      a_h[mt] = *(const bf16x8*)p;
      a_l[mt] = *(const bf16x8*)(p + 32);
    }
#pragma unroll
    for (int nt = 0; nt < 3; ++nt) {
      const ushort* p = &Bs[(n0 + nt * 16 + l15) * 72 + quad * 8];
      b_h[nt] = *(const bf16x8*)p;
      b_l[nt] = *(const bf16x8*)(p + 32);
    }
#pragma unroll
    for (int mt = 0; mt < 4; ++mt)
#pragma unroll
      for (int nt = 0; nt < 3; ++nt) {
        acc[mt][nt] = __builtin_amdgcn_mfma_f32_16x16x32_bf16(a_h[mt], b_h[nt], acc[mt][nt], 0, 0, 0);
        acc[mt][nt] = __builtin_amdgcn_mfma_f32_16x16x32_bf16(a_h[mt], b_l[nt], acc[mt][nt], 0, 0, 0);
        acc[mt][nt] = __builtin_amdgcn_mfma_f32_16x16x32_bf16(a_l[mt], b_h[nt], acc[mt][nt], 0, 0, 0);
      }
  }
  float* Pp = P + (size_t)ks * TS * NB * 192;
#pragma unroll
  for (int mt = 0; mt < 4; ++mt) {
    const int rbase = row0 + mt * 16 + quad * 4;
#pragma unroll
    for (int nt = 0; nt < 3; ++nt) {
      const int col = n0 + nt * 16 + l15;
#pragma unroll
      for (int r = 0; r < 4; ++r)
        Pp[(size_t)(rbase + r) * 192 + col] = acc[mt][nt][r];
    }
  }
}

// ---------------- C1: fused split-K reduce + per-chunk intra + outer sums ----------------
__global__ __launch_bounds__(256) void k_chunkred(
    const float* __restrict__ P, const float* __restrict__ bcomb,
    const float* __restrict__ decay, float* __restrict__ Qg,
    float* __restrict__ Yb, float* __restrict__ O) {
  const int c = blockIdx.x;
  const int b = blockIdx.y;
  const int s0 = c * 32;
  const int tid = threadIdx.x;
  __shared__ float Qs[32][68], Ks[32][68], Vs[32][68];
  __shared__ float Ss[32][36];
  __shared__ float dec[32];
  const size_t NTOT = (size_t)TS * NB * 192;

  for (int idx = tid; idx < 32 * 48; idx += 256) {
    const int r = idx / 48, cq = (idx % 48) * 4;
    const size_t g = (size_t)(b * TS + s0 + r) * 192 + cq;
    float4 a = *(const float4*)&P[g];
    const float4 b2 = *(const float4*)&P[NTOT + g];
    const float4 c2 = *(const float4*)&P[2 * NTOT + g];
    const float4 d2 = *(const float4*)&P[3 * NTOT + g];
    const float4 bi = *(const float4*)&bcomb[cq];
    a.x += b2.x + c2.x + d2.x + bi.x;
    a.y += b2.y + c2.y + d2.y + bi.y;
    a.z += b2.z + c2.z + d2.z + bi.z;
    a.w += b2.w + c2.w + d2.w + bi.w;
    if (cq < 64) {
      *(float4*)&Qs[r][cq] = a;
      *(float4*)&Qg[(size_t)(b * TS + s0 + r) * KD + cq] = a;
    } else if (cq < 128) {
      *(float4*)&Ks[r][cq - 64] = a;
    } else {
      *(float4*)&Vs[r][cq - 128] = a;
    }
  }
  if (tid < 32) dec[tid] = decay[s0 + tid];
  __syncthreads();

  {
    const int sc = (tid & 15) * 2;
    const int tr = (tid >> 4) * 2;
    float a00 = 0.f, a01 = 0.f, a10 = 0.f, a11 = 0.f;
#pragma unroll
    for (int k = 0; k < 64; k += 4) {
      const float4 q0 = *(const float4*)&Qs[tr][k];
      const float4 q1 = *(const float4*)&Qs[tr + 1][k];
      const float4 v0 = *(const float4*)&Vs[sc][k];
      const float4 v1 = *(const float4*)&Vs[sc + 1][k];
      a00 += q0.x * v0.x + q0.y * v0.y + q0.z * v0.z + q0.w * v0.w;
      a01 += q0.x * v1.x + q0.y * v1.y + q0.z * v1.z + q0.w * v1.w;
      a10 += q1.x * v0.x + q1.y * v0.y + q1.z * v0.z + q1.w * v0.w;
      a11 += q1.x * v1.x + q1.y * v1.y + q1.z * v1.z + q1.w * v1.w;
    }
    const float d0 = dec[sc], d1 = dec[sc + 1];
    Ss[tr][sc]         = (sc     <= tr)     ? a00 * d0 : 0.f;
    Ss[tr][sc + 1]     = (sc + 1 <= tr)     ? a01 * d1 : 0.f;
    Ss[tr + 1][sc]     = (sc     <= tr + 1) ? a10 * d0 : 0.f;
    Ss[tr + 1][sc + 1] = (sc + 1 <= tr + 1) ? a11 * d1 : 0.f;
  }

  float o[4][4];
#pragma unroll
  for (int i = 0; i < 4; ++i)
#pragma unroll
    for (int j = 0; j < 4; ++j) o[i][j] = 0.f;
  {
    const int kx = (tid & 15) * 4;
    const int nx = (tid >> 4) * 4;
#pragma unroll
    for (int s = 0; s < 32; ++s) {
      const float ds = dec[s];
      float4 v4 = *(const float4*)&Vs[s][kx];
      const float4 k4 = *(const float4*)&Ks[s][nx];
      v4.x *= ds; v4.y *= ds; v4.z *= ds; v4.w *= ds;
      o[0][0] += v4.x * k4.x; o[0][1] += v4.x * k4.y; o[0][2] += v4.x * k4.z; o[0][3] += v4.x * k4.w;
      o[1][0] += v4.y * k4.x; o[1][1] += v4.y * k4.y; o[1][2] += v4.y * k4.z; o[1][3] += v4.y * k4.w;
      o[2][0] += v4.z * k4.x; o[2][1] += v4.z * k4.y; o[2][2] += v4.z * k4.z; o[2][3] += v4.z * k4.w;
      o[3][0] += v4.w * k4.x; o[3][1] += v4.w * k4.y; o[3][2] += v4.w * k4.z; o[3][3] += v4.w * k4.w;
    }
  }
  __syncthreads();

  {
    const int nx = (tid & 15) * 4;
    const int tr = (tid >> 4) * 2;
    float y0[4] = {0.f, 0.f, 0.f, 0.f};
    float y1[4] = {0.f, 0.f, 0.f, 0.f};
#pragma unroll
    for (int s = 0; s < 32; s += 4) {
      const float4 sa = *(const float4*)&Ss[tr][s];
      const float4 sb = *(const float4*)&Ss[tr + 1][s];
#pragma unroll
      for (int u = 0; u < 4; ++u) {
        const float4 k4 = *(const float4*)&Ks[s + u][nx];
        const float su0 = (u == 0) ? sa.x : (u == 1) ? sa.y : (u == 2) ? sa.z : sa.w;
        const float su1 = (u == 0) ? sb.x : (u == 1) ? sb.y : (u == 2) ? sb.z : sb.w;
        y0[0] += su0 * k4.x; y0[1] += su0 * k4.y; y0[2] += su0 * k4.z; y0[3] += su0 * k4.w;
        y1[0] += su1 * k4.x; y1[1] += su1 * k4.y; y1[2] += su1 * k4.z; y1[3] += su1 * k4.w;
      }
    }
    float4 w0, w1;
    w0.x = y0[0]; w0.y = y0[1]; w0.z = y0[2]; w0.w = y0[3];
    w1.x = y1[0]; w1.y = y1[1]; w1.z = y1[2]; w1.w = y1[3];
    *(float4*)&Yb[(size_t)(b * TS + s0 + tr) * KD + nx] = w0;
    *(float4*)&Yb[(size_t)(b * TS + s0 + tr + 1) * KD + nx] = w1;
  }

  {
    const int kx = (tid & 15) * 4;
    const int nx = (tid >> 4) * 4;
    const size_t base = ((size_t)(b * 64 + c) * 64) * 64;
#pragma unroll
    for (int i = 0; i < 4; ++i) {
      float4 w;
      w.x = o[i][0]; w.y = o[i][1]; w.z = o[i][2]; w.w = o[i][3];
      *(float4*)&O[base + (size_t)(kx + i) * 64 + nx] = w;
    }
  }
}

// ---------------- C2: exclusive prefix over chunks (O -> St) ----------------
__global__ __launch_bounds__(256) void k_scan(const float* __restrict__ O,
                                              float* __restrict__ St) {
  const int e = blockIdx.x * 256 + threadIdx.x;
  const int b = blockIdx.y;
  const float* op = O + (size_t)b * 64 * 4096 + e;
  float* sp = St + (size_t)b * 64 * 4096 + e;
  float run = 0.f;
  for (int c = 0; c < 64; ++c) {
    sp[(size_t)c * 4096] = run;
    run += op[(size_t)c * 4096];
  }
}

// ---------------- C3: fused inter-chunk attention + output GEMM ----------------
// grid (64, 4), 256 threads. y = Yb + Q@St[c], out = y @ W_o + b_o.
__global__ __launch_bounds__(256) void k_interout(
    const float* __restrict__ St, const float* __restrict__ Qg,
    const float* __restrict__ Yb, const float* __restrict__ Wo,
    const float* __restrict__ bo, float* __restrict__ out) {
  const int c = blockIdx.x;
  const int b = blockIdx.y;
  const int t0 = c * 32;
  const int tid = threadIdx.x;
  __shared__ float Sts[64][68];
  __shared__ float Qs[32][68];
  __shared__ float Yrow[32][68];

  {
    const size_t sb = ((size_t)b * 64 + c) * 4096;
#pragma unroll
    for (int g = 0; g < 4; ++g) {
      const int idx = g * 256 + tid;
      const int k = idx >> 4, n = (idx & 15) * 4;
      *(float4*)&Sts[k][n] = *(const float4*)&St[sb + (size_t)k * 64 + n];
    }
  }
#pragma unroll
  for (int i = 0; i < 2; ++i) {
    const int idx = i * 256 + tid;
    const int r = idx >> 4, q = (idx & 15) * 4;
    *(float4*)&Qs[r][q] = *(const float4*)&Qg[(size_t)(b * TS + t0 + r) * KD + q];
    *(float4*)&Yrow[r][q] = *(const float4*)&Yb[(size_t)(b * TS + t0 + r) * KD + q];
  }
  __syncthreads();

  {
    const int nx = (tid & 15) * 4;
    const int tr = (tid >> 4) * 2;
    float y0[4] = {0.f, 0.f, 0.f, 0.f};
    float y1[4] = {0.f, 0.f, 0.f, 0.f};
#pragma unroll
    for (int k = 0; k < 64; k += 4) {
      const float4 q0 = *(const float4*)&Qs[tr][k];
      const float4 q1 = *(const float4*)&Qs[tr + 1][k];
#pragma unroll
      for (int u = 0; u < 4; ++u) {
        const float4 s4 = *(const float4*)&Sts[k + u][nx];
        const float a0 = (u == 0) ? q0.x : (u == 1) ? q0.y : (u == 2) ? q0.z : q0.w;
        const float a1 = (u == 0) ? q1.x : (u == 1) ? q1.y : (u == 2) ? q1.z : q1.w;
        y0[0] += a0 * s4.x; y0[1] += a0 * s4.y; y0[2] += a0 * s4.z; y0[3] += a0 * s4.w;
        y1[0] += a1 * s4.x; y1[1] += a1 * s4.y; y1[2] += a1 * s4.z; y1[3] += a1 * s4.w;
      }
    }
    float4 p0 = *(const float4*)&Yrow[tr][nx];
    float4 p1 = *(const float4*)&Yrow[tr + 1][nx];
    p0.x += y0[0]; p0.y += y0[1]; p0.z += y0[2]; p0.w += y0[3];
    p1.x += y1[0]; p1.y += y1[1]; p1.z += y1[2]; p1.w += y1[3];
    *(float4*)&Yrow[tr][nx] = p0;
    *(float4*)&Yrow[tr + 1][nx] = p1;
  }
  __syncthreads();

  const int d0 = tid * 4;
  const float4 b4 = *(const float4*)&bo[d0];
#pragma unroll
  for (int pass = 0; pass < 2; ++pass) {
    float acc[16][4];
#pragma unroll
    for (int r = 0; r < 16; ++r)
#pragma unroll
      for (int j = 0; j < 4; ++j) acc[r][j] = 0.f;
    for (int k = 0; k < 64; k += 4) {
      const float4 w0 = *(const float4*)&Wo[(size_t)(k + 0) * DM + d0];
      const float4 w1 = *(const float4*)&Wo[(size_t)(k + 1) * DM + d0];
      const float4 w2 = *(const float4*)&Wo[(size_t)(k + 2) * DM + d0];
      const float4 w3 = *(const float4*)&Wo[(size_t)(k + 3) * DM + d0];
#pragma unroll
      for (int r = 0; r < 16; ++r) {
        const float4 ys = *(const float4*)&Yrow[pass * 16 + r][k];
        acc[r][0] += ys.x * w0.x + ys.y * w1.x + ys.z * w2.x + ys.w * w3.x;
        acc[r][1] += ys.x * w0.y + ys.y * w1.y + ys.z * w2.y + ys.w * w3.y;
        acc[r][2] += ys.x * w0.z + ys.y * w1.z + ys.z * w2.z + ys.w * w3.z;
        acc[r][3] += ys.x * w0.w + ys.y * w1.w + ys.z * w2.w + ys.w * w3.w;
      }
    }
#pragma unroll
    for (int r = 0; r < 16; ++r) {
      float4 w;
      w.x = acc[r][0] + b4.x;
      w.y = acc[r][1] + b4.y;
      w.z = acc[r][2] + b4.z;
      w.w = acc[r][3] + b4.w;
      *(float4*)&out[(size_t)(b * TS + t0 + pass * 16 + r) * DM + d0] = w;
    }
  }
}

extern "C" void kernel_launch(void* const* d_in, const int* in_sizes, int n_in,
                              void* d_out, int out_size, void* d_ws, size_t ws_size,
                              hipStream_t stream) {
  const float* x     = (const float*)d_in[0];
  const float* W_pre = (const float*)d_in[1];
  const float* b_pre = (const float*)d_in[2];
  const float* Qf    = (const float*)d_in[3];
  const float* Kf    = (const float*)d_in[4];
  const float* W_v   = (const float*)d_in[5];
  const float* b_v   = (const float*)d_in[6];
  const float* W_o   = (const float*)d_in[7];
  const float* b_o   = (const float*)d_in[8];
  const float* decay = (const float*)d_in[9];
  float* out = (float*)d_out;
  float* ws = (float*)d_ws;

  ushort* WT_hi = (ushort*)(ws + WTH_OFF);
  ushort* WT_lo = (ushort*)(ws + WTL_OFF);
  float* bcomb = ws + BC_OFF;
  float* Qg    = ws + QG_OFF;
  float* P     = ws + P_OFF;
  float* Pf    = ws + PF_OFF;
  float* St    = ws + ST_OFF;
  float* O     = ws + O_OFF;
  float* Yb    = ws + YB_OFF;

  k_prep<<<dim3(16, 2, 16), 256, 0, stream>>>(W_pre, Qf, Kf, Pf);
  k_fred<<<dim3(48), 256, 0, stream>>>(Pf, W_v, b_pre, Qf, Kf, b_v,
                                       WT_hi, WT_lo, bcomb);
  k_qkv<<<dim3(NB * TS / 64, 4), 256, 0, stream>>>(x, WT_hi, WT_lo, P);
  k_chunkred<<<dim3(TS / 32, NB), 256, 0, stream>>>(P, bcomb, decay, Qg, Yb, O);
  k_scan<<<dim3(16, NB), 256, 0, stream>>>(O, St);
  k_interout<<<dim3(TS / 32, NB), 256, 0, stream>>>(St, Qg, Yb, W_o, b_o, out);
}

// Round 9
// 180.933 us; speedup vs baseline: 1.1323x; 1.0849x over previous
//
#include <hip/hip_runtime.h>

#define TS 2048   // seq len
#define DM 1024   // d_model
#define KD 64     // k
#define NB 4      // batch

// ---------- workspace layout (float offsets) ----------
// WT_hi [192][1024] ushort : rows 0-63 Wq^T, 64-127 Wk^T, 128-191 Wv^T (bf16 hi)
// WT_lo [192][1024] ushort : bf16 residual (lo)
// bcomb [192] f32          : bq | bk | bv
// Qg    [8192][64] f32     : Q-only (k_chunkred -> k_interout)
// P     [4][8192][192] f32 : split-K partials (k_qkv -> k_chunkred)
// Pf    [16][128][1024] f32: fold partials (k_prep -> k_fred), overlays P front
// St    [4][64][64][64] f32: exclusive chunk-prefix (k_scan -> k_interout),
//                            overlays dead P region (P consumed by k_chunkred)
// O     [4][64][64][64] f32: per-chunk outer sums (k_chunkred -> k_scan)
// Yb    [8192][64] f32     : intra-chunk Y (k_chunkred -> k_interout)
#define WTH_OFF 0
#define WTL_OFF 98304
#define BC_OFF  196608
#define QG_OFF  196864
#define P_OFF   1769728
#define PF_OFF  (P_OFF)
#define ST_OFF  (P_OFF)
#define O_OFF   8061184
#define YB_OFF  9109760

typedef __attribute__((ext_vector_type(8))) short bf16x8;
typedef __attribute__((ext_vector_type(4))) float f32x4;

__device__ __forceinline__ ushort f2bf(float f) {
  unsigned u = __float_as_uint(f);
  unsigned r = u + 0x7FFFu + ((u >> 16) & 1u);
  return (ushort)(r >> 16);
}
__device__ __forceinline__ float bf2f(ushort h) {
  return __uint_as_float(((unsigned)h) << 16);
}

// ---------------- A1: split-K MFMA fold partials ----------------
__global__ __launch_bounds__(256) void k_prep(
    const float* __restrict__ W_pre, const float* __restrict__ Qf,
    const float* __restrict__ Kf, float* __restrict__ Pf) {
  const int d0 = blockIdx.x * 64;
  const int f = blockIdx.y;
  const int ks = blockIdx.z;
  const float* __restrict__ F = f ? Kf : Qf;
  const int tid = threadIdx.x;
  const int wave = tid >> 6, lane = tid & 63;
  const int quad = lane >> 4, l15 = lane & 15;
  __shared__ ushort As[64 * 72];
  __shared__ ushort Bs[64 * 72];
  f32x4 acc[4];
#pragma unroll
  for (int nt = 0; nt < 4; ++nt) acc[nt] = (f32x4){0.f, 0.f, 0.f, 0.f};

  const int ra = tid >> 3;
  const int c4 = (tid & 7) * 4;
  float4 aw[2];
  float bw[8];
  int t0 = ks * 128;
#pragma unroll
  for (int i = 0; i < 2; ++i)
    aw[i] = *(const float4*)&W_pre[(size_t)(d0 + i * 32 + ra) * TS + t0 + c4];
#pragma unroll
  for (int h = 0; h < 2; ++h)
#pragma unroll
    for (int u = 0; u < 4; ++u)
      bw[h * 4 + u] = F[(size_t)(t0 + (wave + 4 * h) * 4 + u) * KD + lane];

  for (int step = 0; step < 4; ++step) {
    __syncthreads();
#pragma unroll
    for (int i = 0; i < 2; ++i) {
      const int r = i * 32 + ra;
      const float4 v = aw[i];
      const ushort h0 = f2bf(v.x), h1 = f2bf(v.y), h2 = f2bf(v.z), h3 = f2bf(v.w);
      *(ushort4*)&As[r * 72 + c4] = make_ushort4(h0, h1, h2, h3);
      *(ushort4*)&As[r * 72 + 32 + c4] = make_ushort4(
          f2bf(v.x - bf2f(h0)), f2bf(v.y - bf2f(h1)),
          f2bf(v.z - bf2f(h2)), f2bf(v.w - bf2f(h3)));
    }
#pragma unroll
    for (int h = 0; h < 2; ++h) {
      const int gg = wave + 4 * h;
      ushort hh[4], ll[4];
#pragma unroll
      for (int u = 0; u < 4; ++u) {
        hh[u] = f2bf(bw[h * 4 + u]);
        ll[u] = f2bf(bw[h * 4 + u] - bf2f(hh[u]));
      }
      *(ushort4*)&Bs[lane * 72 + gg * 4] = make_ushort4(hh[0], hh[1], hh[2], hh[3]);
      *(ushort4*)&Bs[lane * 72 + 32 + gg * 4] = make_ushort4(ll[0], ll[1], ll[2], ll[3]);
    }
    __syncthreads();
    if (step < 3) {
      const int t1 = t0 + 32;
#pragma unroll
      for (int i = 0; i < 2; ++i)
        aw[i] = *(const float4*)&W_pre[(size_t)(d0 + i * 32 + ra) * TS + t1 + c4];
#pragma unroll
      for (int h = 0; h < 2; ++h)
#pragma unroll
        for (int u = 0; u < 4; ++u)
          bw[h * 4 + u] = F[(size_t)(t1 + (wave + 4 * h) * 4 + u) * KD + lane];
    }
    const ushort* ap = &As[(wave * 16 + l15) * 72 + quad * 8];
    const bf16x8 a_h = *(const bf16x8*)ap;
    const bf16x8 a_l = *(const bf16x8*)(ap + 32);
#pragma unroll
    for (int nt = 0; nt < 4; ++nt) {
      const ushort* bp = &Bs[(nt * 16 + l15) * 72 + quad * 8];
      const bf16x8 b_h = *(const bf16x8*)bp;
      const bf16x8 b_l = *(const bf16x8*)(bp + 32);
      acc[nt] = __builtin_amdgcn_mfma_f32_16x16x32_bf16(a_h, b_h, acc[nt], 0, 0, 0);
      acc[nt] = __builtin_amdgcn_mfma_f32_16x16x32_bf16(a_h, b_l, acc[nt], 0, 0, 0);
      acc[nt] = __builtin_amdgcn_mfma_f32_16x16x32_bf16(a_l, b_h, acc[nt], 0, 0, 0);
    }
    t0 += 32;
  }
#pragma unroll
  for (int nt = 0; nt < 4; ++nt) {
    const int n = f * 64 + nt * 16 + l15;
#pragma unroll
    for (int r = 0; r < 4; ++r) {
      const int d = d0 + wave * 16 + quad * 4 + r;
      Pf[((size_t)ks * 128 + n) * DM + d] = acc[nt][r];
    }
  }
}

// ---------------- A2: reduce fold partials -> WT hi/lo; Wv transpose; bias ----------------
__global__ __launch_bounds__(256) void k_fred(
    const float* __restrict__ Pf, const float* __restrict__ Wv,
    const float* __restrict__ b_pre, const float* __restrict__ Qf,
    const float* __restrict__ Kf, const float* __restrict__ bv,
    ushort* __restrict__ WT_hi, ushort* __restrict__ WT_lo,
    float* __restrict__ bcomb) {
  const int bx = blockIdx.x;
  const int tid = threadIdx.x;
  if (bx < 32) {
    const int n0 = bx * 4;
    const int d4 = tid * 4;
#pragma unroll
    for (int j = 0; j < 4; ++j) {
      const int n = n0 + j;
      float4 s = {0.f, 0.f, 0.f, 0.f};
#pragma unroll
      for (int ks = 0; ks < 16; ++ks) {
        const float4 v = *(const float4*)&Pf[((size_t)ks * 128 + n) * DM + d4];
        s.x += v.x; s.y += v.y; s.z += v.z; s.w += v.w;
      }
      const ushort h0 = f2bf(s.x), h1 = f2bf(s.y), h2 = f2bf(s.z), h3 = f2bf(s.w);
      *(ushort4*)&WT_hi[(size_t)n * DM + d4] = make_ushort4(h0, h1, h2, h3);
      *(ushort4*)&WT_lo[(size_t)n * DM + d4] = make_ushort4(
          f2bf(s.x - bf2f(h0)), f2bf(s.y - bf2f(h1)),
          f2bf(s.z - bf2f(h2)), f2bf(s.w - bf2f(h3)));
    }
    const float* __restrict__ F = (n0 < 64) ? Qf : Kf;
    const int c0 = n0 & 63;
    __shared__ float bred[4][256];
    float p[4] = {0.f, 0.f, 0.f, 0.f};
#pragma unroll
    for (int u = 0; u < 8; ++u) {
      const int t = tid * 8 + u;
      const float bp = b_pre[t];
#pragma unroll
      for (int j = 0; j < 4; ++j) p[j] += bp * F[(size_t)t * KD + c0 + j];
    }
#pragma unroll
    for (int j = 0; j < 4; ++j) bred[j][tid] = p[j];
    __syncthreads();
    for (int s = 128; s > 0; s >>= 1) {
      if (tid < s) {
#pragma unroll
        for (int j = 0; j < 4; ++j) bred[j][tid] += bred[j][tid + s];
      }
      __syncthreads();
    }
    if (tid < 4) bcomb[n0 + tid] = bred[tid][0];
  } else {
    const int n0 = 128 + (bx - 32) * 4;
    const int d4 = tid * 4;
#pragma unroll
    for (int j = 0; j < 4; ++j) {
      const int c = n0 - 128 + j;
      float v[4];
#pragma unroll
      for (int i = 0; i < 4; ++i) v[i] = Wv[(size_t)(d4 + i) * KD + c];
      const ushort h0 = f2bf(v[0]), h1 = f2bf(v[1]), h2 = f2bf(v[2]), h3 = f2bf(v[3]);
      *(ushort4*)&WT_hi[(size_t)(n0 + j) * DM + d4] = make_ushort4(h0, h1, h2, h3);
      *(ushort4*)&WT_lo[(size_t)(n0 + j) * DM + d4] = make_ushort4(
          f2bf(v[0] - bf2f(h0)), f2bf(v[1] - bf2f(h1)),
          f2bf(v[2] - bf2f(h2)), f2bf(v[3] - bf2f(h3)));
    }
    if (tid < 4) bcomb[n0 + tid] = bv[n0 - 128 + tid];
  }
}

// ---------------- B: split-K MFMA bf16x3 GEMM  P[ks] = x[:, ks*256:+256] @ W ----------------
__global__ __launch_bounds__(256) void k_qkv(
    const float* __restrict__ x, const ushort* __restrict__ WT_hi,
    const ushort* __restrict__ WT_lo, float* __restrict__ P) {
  const int row0 = blockIdx.x * 64;
  const int ks = blockIdx.y;
  const int tid = threadIdx.x;
  const int wave = tid >> 6, lane = tid & 63;
  const int quad = lane >> 4, l15 = lane & 15;
  const int n0 = wave * 48;
  __shared__ ushort As[64 * 72];
  __shared__ ushort Bs[192 * 72];
  f32x4 acc[4][3];
#pragma unroll
  for (int mt = 0; mt < 4; ++mt)
#pragma unroll
    for (int nt = 0; nt < 3; ++nt) acc[mt][nt] = (f32x4){0.f, 0.f, 0.f, 0.f};

  for (int step = 0; step < 8; ++step) {
    const int kk = ks * 256 + step * 32;
    __syncthreads();
#pragma unroll
    for (int i = 0; i < 2; ++i) {
      const int idx = i * 256 + tid;
      const int r = idx >> 3, c4 = (idx & 7) * 4;
      const float4 v = *(const float4*)&x[(size_t)(row0 + r) * DM + kk + c4];
      const ushort h0 = f2bf(v.x), h1 = f2bf(v.y), h2 = f2bf(v.z), h3 = f2bf(v.w);
      *(ushort4*)&As[r * 72 + c4] = make_ushort4(h0, h1, h2, h3);
      *(ushort4*)&As[r * 72 + 32 + c4] = make_ushort4(
          f2bf(v.x - bf2f(h0)), f2bf(v.y - bf2f(h1)),
          f2bf(v.z - bf2f(h2)), f2bf(v.w - bf2f(h3)));
    }
#pragma unroll
    for (int i = 0; i < 6; ++i) {
      const int idx = i * 256 + tid;
      const int half = idx >= 768;
      const int j = half ? idx - 768 : idx;
      const int n = j >> 2, ch = j & 3;
      const ushort* src = (half ? WT_lo : WT_hi) + (size_t)n * DM + kk + ch * 8;
      *(float4*)&Bs[n * 72 + half * 32 + ch * 8] = *(const float4*)src;
    }
    __syncthreads();
    bf16x8 a_h[4], a_l[4], b_h[3], b_l[3];
#pragma unroll
    for (int mt = 0; mt < 4; ++mt) {
      const ushort* p = &As[(mt * 16 + l15) * 72 + quad * 8];
      a_h[mt] = *(const bf16x8*)p;
      a_l[mt] = *(const bf16x8*)(p + 32);
    }
#pragma unroll
    for (int nt = 0; nt < 3; ++nt) {
      const ushort* p = &Bs[(n0 + nt * 16 + l15) * 72 + quad * 8];
      b_h[nt] = *(const bf16x8*)p;
      b_l[nt] = *(const bf16x8*)(p + 32);
    }
#pragma unroll
    for (int mt = 0; mt < 4; ++mt)
#pragma unroll
      for (int nt = 0; nt < 3; ++nt) {
        acc[mt][nt] = __builtin_amdgcn_mfma_f32_16x16x32_bf16(a_h[mt], b_h[nt], acc[mt][nt], 0, 0, 0);
        acc[mt][nt] = __builtin_amdgcn_mfma_f32_16x16x32_bf16(a_h[mt], b_l[nt], acc[mt][nt], 0, 0, 0);
        acc[mt][nt] = __builtin_amdgcn_mfma_f32_16x16x32_bf16(a_l[mt], b_h[nt], acc[mt][nt], 0, 0, 0);
      }
  }
  float* Pp = P + (size_t)ks * TS * NB * 192;
#pragma unroll
  for (int mt = 0; mt < 4; ++mt) {
    const int rbase = row0 + mt * 16 + quad * 4;
#pragma unroll
    for (int nt = 0; nt < 3; ++nt) {
      const int col = n0 + nt * 16 + l15;
#pragma unroll
      for (int r = 0; r < 4; ++r)
        Pp[(size_t)(rbase + r) * 192 + col] = acc[mt][nt][r];
    }
  }
}

// ---------------- C1: fused split-K reduce + per-chunk intra + outer sums ----------------
__global__ __launch_bounds__(256) void k_chunkred(
    const float* __restrict__ P, const float* __restrict__ bcomb,
    const float* __restrict__ decay, float* __restrict__ Qg,
    float* __restrict__ Yb, float* __restrict__ O) {
  const int c = blockIdx.x;
  const int b = blockIdx.y;
  const int s0 = c * 32;
  const int tid = threadIdx.x;
  __shared__ float Qs[32][68], Ks[32][68], Vs[32][68];
  __shared__ float Ss[32][36];
  __shared__ float dec[32];
  const size_t NTOT = (size_t)TS * NB * 192;

  for (int idx = tid; idx < 32 * 48; idx += 256) {
    const int r = idx / 48, cq = (idx % 48) * 4;
    const size_t g = (size_t)(b * TS + s0 + r) * 192 + cq;
    float4 a = *(const float4*)&P[g];
    const float4 b2 = *(const float4*)&P[NTOT + g];
    const float4 c2 = *(const float4*)&P[2 * NTOT + g];
    const float4 d2 = *(const float4*)&P[3 * NTOT + g];
    const float4 bi = *(const float4*)&bcomb[cq];
    a.x += b2.x + c2.x + d2.x + bi.x;
    a.y += b2.y + c2.y + d2.y + bi.y;
    a.z += b2.z + c2.z + d2.z + bi.z;
    a.w += b2.w + c2.w + d2.w + bi.w;
    if (cq < 64) {
      *(float4*)&Qs[r][cq] = a;
      *(float4*)&Qg[(size_t)(b * TS + s0 + r) * KD + cq] = a;
    } else if (cq < 128) {
      *(float4*)&Ks[r][cq - 64] = a;
    } else {
      *(float4*)&Vs[r][cq - 128] = a;
    }
  }
  if (tid < 32) dec[tid] = decay[s0 + tid];
  __syncthreads();

  {
    const int sc = (tid & 15) * 2;
    const int tr = (tid >> 4) * 2;
    float a00 = 0.f, a01 = 0.f, a10 = 0.f, a11 = 0.f;
#pragma unroll
    for (int k = 0; k < 64; k += 4) {
      const float4 q0 = *(const float4*)&Qs[tr][k];
      const float4 q1 = *(const float4*)&Qs[tr + 1][k];
      const float4 v0 = *(const float4*)&Vs[sc][k];
      const float4 v1 = *(const float4*)&Vs[sc + 1][k];
      a00 += q0.x * v0.x + q0.y * v0.y + q0.z * v0.z + q0.w * v0.w;
      a01 += q0.x * v1.x + q0.y * v1.y + q0.z * v1.z + q0.w * v1.w;
      a10 += q1.x * v0.x + q1.y * v0.y + q1.z * v0.z + q1.w * v0.w;
      a11 += q1.x * v1.x + q1.y * v1.y + q1.z * v1.z + q1.w * v1.w;
    }
    const float d0 = dec[sc], d1 = dec[sc + 1];
    Ss[tr][sc]         = (sc     <= tr)     ? a00 * d0 : 0.f;
    Ss[tr][sc + 1]     = (sc + 1 <= tr)     ? a01 * d1 : 0.f;
    Ss[tr + 1][sc]     = (sc     <= tr + 1) ? a10 * d0 : 0.f;
    Ss[tr + 1][sc + 1] = (sc + 1 <= tr + 1) ? a11 * d1 : 0.f;
  }

  float o[4][4];
#pragma unroll
  for (int i = 0; i < 4; ++i)
#pragma unroll
    for (int j = 0; j < 4; ++j) o[i][j] = 0.f;
  {
    const int kx = (tid & 15) * 4;
    const int nx = (tid >> 4) * 4;
#pragma unroll
    for (int s = 0; s < 32; ++s) {
      const float ds = dec[s];
      float4 v4 = *(const float4*)&Vs[s][kx];
      const float4 k4 = *(const float4*)&Ks[s][nx];
      v4.x *= ds; v4.y *= ds; v4.z *= ds; v4.w *= ds;
      o[0][0] += v4.x * k4.x; o[0][1] += v4.x * k4.y; o[0][2] += v4.x * k4.z; o[0][3] += v4.x * k4.w;
      o[1][0] += v4.y * k4.x; o[1][1] += v4.y * k4.y; o[1][2] += v4.y * k4.z; o[1][3] += v4.y * k4.w;
      o[2][0] += v4.z * k4.x; o[2][1] += v4.z * k4.y; o[2][2] += v4.z * k4.z; o[2][3] += v4.z * k4.w;
      o[3][0] += v4.w * k4.x; o[3][1] += v4.w * k4.y; o[3][2] += v4.w * k4.z; o[3][3] += v4.w * k4.w;
    }
  }
  __syncthreads();

  {
    const int nx = (tid & 15) * 4;
    const int tr = (tid >> 4) * 2;
    float y0[4] = {0.f, 0.f, 0.f, 0.f};
    float y1[4] = {0.f, 0.f, 0.f, 0.f};
#pragma unroll
    for (int s = 0; s < 32; s += 4) {
      const float4 sa = *(const float4*)&Ss[tr][s];
      const float4 sb = *(const float4*)&Ss[tr + 1][s];
#pragma unroll
      for (int u = 0; u < 4; ++u) {
        const float4 k4 = *(const float4*)&Ks[s + u][nx];
        const float su0 = (u == 0) ? sa.x : (u == 1) ? sa.y : (u == 2) ? sa.z : sa.w;
        const float su1 = (u == 0) ? sb.x : (u == 1) ? sb.y : (u == 2) ? sb.z : sb.w;
        y0[0] += su0 * k4.x; y0[1] += su0 * k4.y; y0[2] += su0 * k4.z; y0[3] += su0 * k4.w;
        y1[0] += su1 * k4.x; y1[1] += su1 * k4.y; y1[2] += su1 * k4.z; y1[3] += su1 * k4.w;
      }
    }
    float4 w0, w1;
    w0.x = y0[0]; w0.y = y0[1]; w0.z = y0[2]; w0.w = y0[3];
    w1.x = y1[0]; w1.y = y1[1]; w1.z = y1[2]; w1.w = y1[3];
    *(float4*)&Yb[(size_t)(b * TS + s0 + tr) * KD + nx] = w0;
    *(float4*)&Yb[(size_t)(b * TS + s0 + tr + 1) * KD + nx] = w1;
  }

  {
    const int kx = (tid & 15) * 4;
    const int nx = (tid >> 4) * 4;
    const size_t base = ((size_t)(b * 64 + c) * 64) * 64;
#pragma unroll
    for (int i = 0; i < 4; ++i) {
      float4 w;
      w.x = o[i][0]; w.y = o[i][1]; w.z = o[i][2]; w.w = o[i][3];
      *(float4*)&O[base + (size_t)(kx + i) * 64 + nx] = w;
    }
  }
}

// ---------------- C2: exclusive prefix over chunks (O -> St) ----------------
__global__ __launch_bounds__(256) void k_scan(const float* __restrict__ O,
                                              float* __restrict__ St) {
  const int e = blockIdx.x * 256 + threadIdx.x;
  const int b = blockIdx.y;
  const float* op = O + (size_t)b * 64 * 4096 + e;
  float* sp = St + (size_t)b * 64 * 4096 + e;
  float run = 0.f;
  for (int c = 0; c < 64; ++c) {
    sp[(size_t)c * 4096] = run;
    run += op[(size_t)c * 4096];
  }
}

// ---------------- C3: fused inter-chunk attention + output GEMM (d-split) ----------------
// grid (64, 4, 4), 512 threads. All z-blocks stage St/Qg/Yb and do the cheap
// inter-attn redundantly; z picks a 256-wide d-slice of the out-GEMM.
// 1024 blocks = 4 blocks/CU = 32 waves/CU (vs 1 blk/4 waves in R8 — the 51 µs
// was exposed latency at 1 wave/SIMD).
__global__ __launch_bounds__(512) void k_interout(
    const float* __restrict__ St, const float* __restrict__ Qg,
    const float* __restrict__ Yb, const float* __restrict__ Wo,
    const float* __restrict__ bo, float* __restrict__ out) {
  const int c = blockIdx.x;
  const int b = blockIdx.y;
  const int z = blockIdx.z;
  const int t0 = c * 32;
  const int tid = threadIdx.x;
  __shared__ float Sts[64][68];
  __shared__ float Qs[32][68];
  __shared__ float Yrow[32][68];

  {
    const size_t sb = ((size_t)b * 64 + c) * 4096;
#pragma unroll
    for (int g = 0; g < 2; ++g) {
      const int idx = g * 512 + tid;
      const int k = idx >> 4, n = (idx & 15) * 4;
      *(float4*)&Sts[k][n] = *(const float4*)&St[sb + (size_t)k * 64 + n];
    }
  }
  {
    const int r = tid >> 4, q = (tid & 15) * 4;
    *(float4*)&Qs[r][q] = *(const float4*)&Qg[(size_t)(b * TS + t0 + r) * KD + q];
    *(float4*)&Yrow[r][q] = *(const float4*)&Yb[(size_t)(b * TS + t0 + r) * KD + q];
  }
  __syncthreads();

  // inter-chunk: Yrow += Qs @ Sts   (thread: 1 row x 4 cols)
  {
    const int nx = (tid & 15) * 4;
    const int tr = tid >> 4;  // 0..31
    float y0[4] = {0.f, 0.f, 0.f, 0.f};
#pragma unroll
    for (int k = 0; k < 64; k += 4) {
      const float4 q0 = *(const float4*)&Qs[tr][k];
#pragma unroll
      for (int u = 0; u < 4; ++u) {
        const float4 s4 = *(const float4*)&Sts[k + u][nx];
        const float a0 = (u == 0) ? q0.x : (u == 1) ? q0.y : (u == 2) ? q0.z : q0.w;
        y0[0] += a0 * s4.x; y0[1] += a0 * s4.y; y0[2] += a0 * s4.z; y0[3] += a0 * s4.w;
      }
    }
    float4 p0 = *(const float4*)&Yrow[tr][nx];
    p0.x += y0[0]; p0.y += y0[1]; p0.z += y0[2]; p0.w += y0[3];
    *(float4*)&Yrow[tr][nx] = p0;
  }
  __syncthreads();

  // out-GEMM slice: thread = 4 rows (wave-uniform) x 4 d-cols
  const int rg = (tid >> 6) * 4;                 // 0,4,..,28 (uniform per wave)
  const int dcol = z * 256 + (tid & 63) * 4;
  const float4 b4 = *(const float4*)&bo[dcol];
  float acc[4][4];
#pragma unroll
  for (int r = 0; r < 4; ++r)
#pragma unroll
    for (int j = 0; j < 4; ++j) acc[r][j] = 0.f;
#pragma unroll 8
  for (int k = 0; k < 64; ++k) {
    const float4 w4 = *(const float4*)&Wo[(size_t)k * DM + dcol];
    const float y0 = Yrow[rg + 0][k];
    const float y1 = Yrow[rg + 1][k];
    const float y2 = Yrow[rg + 2][k];
    const float y3 = Yrow[rg + 3][k];
    acc[0][0] += y0 * w4.x; acc[0][1] += y0 * w4.y; acc[0][2] += y0 * w4.z; acc[0][3] += y0 * w4.w;
    acc[1][0] += y1 * w4.x; acc[1][1] += y1 * w4.y; acc[1][2] += y1 * w4.z; acc[1][3] += y1 * w4.w;
    acc[2][0] += y2 * w4.x; acc[2][1] += y2 * w4.y; acc[2][2] += y2 * w4.z; acc[2][3] += y2 * w4.w;
    acc[3][0] += y3 * w4.x; acc[3][1] += y3 * w4.y; acc[3][2] += y3 * w4.z; acc[3][3] += y3 * w4.w;
  }
#pragma unroll
  for (int r = 0; r < 4; ++r) {
    float4 w;
    w.x = acc[r][0] + b4.x;
    w.y = acc[r][1] + b4.y;
    w.z = acc[r][2] + b4.z;
    w.w = acc[r][3] + b4.w;
    *(float4*)&out[(size_t)(b * TS + t0 + rg + r) * DM + dcol] = w;
  }
}

extern "C" void kernel_launch(void* const* d_in, const int* in_sizes, int n_in,
                              void* d_out, int out_size, void* d_ws, size_t ws_size,
                              hipStream_t stream) {
  const float* x     = (const float*)d_in[0];
  const float* W_pre = (const float*)d_in[1];
  const float* b_pre = (const float*)d_in[2];
  const float* Qf    = (const float*)d_in[3];
  const float* Kf    = (const float*)d_in[4];
  const float* W_v   = (const float*)d_in[5];
  const float* b_v   = (const float*)d_in[6];
  const float* W_o   = (const float*)d_in[7];
  const float* b_o   = (const float*)d_in[8];
  const float* decay = (const float*)d_in[9];
  float* out = (float*)d_out;
  float* ws = (float*)d_ws;

  ushort* WT_hi = (ushort*)(ws + WTH_OFF);
  ushort* WT_lo = (ushort*)(ws + WTL_OFF);
  float* bcomb = ws + BC_OFF;
  float* Qg    = ws + QG_OFF;
  float* P     = ws + P_OFF;
  float* Pf    = ws + PF_OFF;
  float* St    = ws + ST_OFF;
  float* O     = ws + O_OFF;
  float* Yb    = ws + YB_OFF;

  k_prep<<<dim3(16, 2, 16), 256, 0, stream>>>(W_pre, Qf, Kf, Pf);
  k_fred<<<dim3(48), 256, 0, stream>>>(Pf, W_v, b_pre, Qf, Kf, b_v,
                                       WT_hi, WT_lo, bcomb);
  k_qkv<<<dim3(NB * TS / 64, 4), 256, 0, stream>>>(x, WT_hi, WT_lo, P);
  k_chunkred<<<dim3(TS / 32, NB), 256, 0, stream>>>(P, bcomb, decay, Qg, Yb, O);
  k_scan<<<dim3(16, NB), 256, 0, stream>>>(O, St);
  k_interout<<<dim3(TS / 32, NB, 4), 512, 0, stream>>>(St, Qg, Yb, W_o, b_o, out);
}